// Round 1
// baseline (102.469 us; speedup 1.0000x reference)
//
#include <hip/hip_runtime.h>
#include <stdint.h>

#define EPS 1e-5f

typedef short bf16x8 __attribute__((ext_vector_type(8)));
typedef float f32x4 __attribute__((ext_vector_type(4)));

constexpr int M = 1024, N = 4096, K = 4096;
constexpr int BM = 64, BN = 128, BK = 64;
constexpr int NTK = K / BK;           // 64 K-steps

// ---------- helpers ----------
__device__ __forceinline__ unsigned short f2bf(float f) {
  union { float f; uint32_t u; } v; v.f = f;
  uint32_t r = (v.u + 0x7fffu + ((v.u >> 16) & 1u)) >> 16;  // RNE
  return (unsigned short)r;
}

// global -> LDS async, 16B per lane. LDS dest must be wave-uniform base;
// HW adds lane*16. Casts via uintptr_t (CK-style); LDS generic ptr low 32
// bits are the LDS offset (4GB-aligned aperture).
__device__ __forceinline__ void gload16(const void* g, void* l) {
  __builtin_amdgcn_global_load_lds(
      (const __attribute__((address_space(1))) void*)(uintptr_t)g,
      (__attribute__((address_space(3))) void*)(uintptr_t)l, 16, 0, 0);
}

// ---------- prep: build bf16 weight, bf16 x, fp32 bias ----------
__global__ __launch_bounds__(256) void prep_kernel(
    const float* __restrict__ wm, const float* __restrict__ wsp,
    const float* __restrict__ nw, const float* __restrict__ bm,
    const float* __restrict__ bsp, const float* __restrict__ nb,
    const float* __restrict__ x,
    unsigned short* __restrict__ w_bf, unsigned short* __restrict__ x_bf,
    float* __restrict__ bias)
{
  const int64_t W4 = (int64_t)N * K / 4;   // 4,194,304 vec4 items
  const int64_t X4 = (int64_t)M * K / 4;   // 1,048,576
  const int64_t B4 = N / 4;                // 1,024
  const int64_t total = W4 + X4 + B4;
  for (int64_t i = (int64_t)blockIdx.x * blockDim.x + threadIdx.x; i < total;
       i += (int64_t)gridDim.x * blockDim.x) {
    if (i < W4) {
      float4 a = ((const float4*)wm)[i];
      float4 s = ((const float4*)wsp)[i];
      float4 n = ((const float4*)nw)[i];
      ushort4 o;
      o.x = f2bf(a.x + n.x * fmaxf(__expf(s.x), EPS));
      o.y = f2bf(a.y + n.y * fmaxf(__expf(s.y), EPS));
      o.z = f2bf(a.z + n.z * fmaxf(__expf(s.z), EPS));
      o.w = f2bf(a.w + n.w * fmaxf(__expf(s.w), EPS));
      ((ushort4*)w_bf)[i] = o;
    } else if (i < W4 + X4) {
      int64_t j = i - W4;
      float4 v = ((const float4*)x)[j];
      ushort4 o;
      o.x = f2bf(v.x); o.y = f2bf(v.y); o.z = f2bf(v.z); o.w = f2bf(v.w);
      ((ushort4*)x_bf)[j] = o;
    } else {
      int64_t j = i - W4 - X4;
      float4 a = ((const float4*)bm)[j];
      float4 s = ((const float4*)bsp)[j];
      float4 n = ((const float4*)nb)[j];
      float4 o;
      o.x = a.x + n.x * fmaxf(__expf(s.x), EPS);
      o.y = a.y + n.y * fmaxf(__expf(s.y), EPS);
      o.z = a.z + n.z * fmaxf(__expf(s.z), EPS);
      o.w = a.w + n.w * fmaxf(__expf(s.w), EPS);
      ((float4*)bias)[j] = o;
    }
  }
}

// ---------- GEMM: out = x_bf @ w_bf^T + bias ----------
// A = x_bf [M][K] bf16 row-major, B = w_bf [N][K] bf16 row-major (B^T form).
// Block: 256 threads = 4 waves (2x2), tile BM=64 x BN=128, BK=64.
// Wave tile 32x64 = 2x4 fragments of 16x16, mfma_f32_16x16x32_bf16.
__global__ __launch_bounds__(256) void gemm_kernel(
    const unsigned short* __restrict__ Abf,
    const unsigned short* __restrict__ Bbf,
    const float* __restrict__ bias,
    float* __restrict__ out)
{
  __shared__ unsigned short lds_mem[2][(BM + BN) * BK];  // 48 KB

  // bijective XCD swizzle: grid=512, 512%8==0
  const int nwg = gridDim.x;
  const int bid = blockIdx.x;
  const int lid = (bid % 8) * (nwg / 8) + bid / 8;
  // bc-major chunks: same-XCD blocks share B panels (4 MB) in XCD L2
  const int bc = lid >> 4;   // N-tile, 0..31
  const int br = lid & 15;   // M-tile, 0..15

  const int tid = threadIdx.x;
  const int lane = tid & 63;
  const int wid = tid >> 6;

  // staging source addresses (per-lane): each lane loads 16B = 8 bf16
  const int srow = wid * 8 + (lane >> 3);   // row within a 32-row pass
  const int scol = (lane & 7) * 8;
  const unsigned short* gA = Abf + (int64_t)(br * BM + srow) * K + scol;
  const unsigned short* gB = Bbf + (int64_t)(bc * BN + srow) * K + scol;

  // wave-uniform LDS bases (HW adds lane*16B which equals row-major layout)
  unsigned short* ldsA0 = &lds_mem[0][0];
  unsigned short* ldsB0 = &lds_mem[0][BM * BK];
  unsigned short* ldsA1 = &lds_mem[1][0];
  unsigned short* ldsB1 = &lds_mem[1][BM * BK];
  const int woff = wid * 8 * BK;  // wave's row offset within a pass

  auto stage = [&](int b, int t) {
    const unsigned short* ga = gA + t * BK;
    const unsigned short* gb = gB + t * BK;
    unsigned short* la = (b ? ldsA1 : ldsA0) + woff;
    unsigned short* lb = (b ? ldsB1 : ldsB0) + woff;
    // A: 64 rows = 2 passes of 32 rows (4 waves x 8 rows)
    gload16(ga,          la);
    gload16(ga + 32 * K, la + 32 * BK);
    // B: 128 rows = 4 passes
    gload16(gb,          lb);
    gload16(gb + 32 * K, lb + 32 * BK);
    gload16(gb + 64 * K, lb + 64 * BK);
    gload16(gb + 96 * K, lb + 96 * BK);
  };

  f32x4 acc[2][4] = {};
  const int fr = lane & 15;
  const int fk = (lane >> 4) << 3;       // k-offset within 32
  const int am = (wid >> 1) * 32;        // wave m-offset in tile
  const int an = (wid & 1) * 64;         // wave n-offset in tile

  stage(0, 0);

  int cur = 0;
  for (int t = 0; t < NTK; ++t) {
    __syncthreads();  // drains vmcnt for buf[cur]'s stage + prior LDS reads
    if (t + 1 < NTK) stage(cur ^ 1, t + 1);
    const unsigned short* lA = cur ? ldsA1 : ldsA0;
    const unsigned short* lB = cur ? ldsB1 : ldsB0;
#pragma unroll
    for (int kk = 0; kk < 2; ++kk) {
      const int ko = kk * 32 + fk;
      bf16x8 a0 = *(const bf16x8*)&lA[(am +  0 + fr) * BK + ko];
      bf16x8 a1 = *(const bf16x8*)&lA[(am + 16 + fr) * BK + ko];
      bf16x8 b0 = *(const bf16x8*)&lB[(an +  0 + fr) * BK + ko];
      bf16x8 b1 = *(const bf16x8*)&lB[(an + 16 + fr) * BK + ko];
      bf16x8 b2 = *(const bf16x8*)&lB[(an + 32 + fr) * BK + ko];
      bf16x8 b3 = *(const bf16x8*)&lB[(an + 48 + fr) * BK + ko];
      acc[0][0] = __builtin_amdgcn_mfma_f32_16x16x32_bf16(a0, b0, acc[0][0], 0, 0, 0);
      acc[0][1] = __builtin_amdgcn_mfma_f32_16x16x32_bf16(a0, b1, acc[0][1], 0, 0, 0);
      acc[0][2] = __builtin_amdgcn_mfma_f32_16x16x32_bf16(a0, b2, acc[0][2], 0, 0, 0);
      acc[0][3] = __builtin_amdgcn_mfma_f32_16x16x32_bf16(a0, b3, acc[0][3], 0, 0, 0);
      acc[1][0] = __builtin_amdgcn_mfma_f32_16x16x32_bf16(a1, b0, acc[1][0], 0, 0, 0);
      acc[1][1] = __builtin_amdgcn_mfma_f32_16x16x32_bf16(a1, b1, acc[1][1], 0, 0, 0);
      acc[1][2] = __builtin_amdgcn_mfma_f32_16x16x32_bf16(a1, b2, acc[1][2], 0, 0, 0);
      acc[1][3] = __builtin_amdgcn_mfma_f32_16x16x32_bf16(a1, b3, acc[1][3], 0, 0, 0);
    }
    cur ^= 1;
  }

  // epilogue: C/D layout (verified m89/m91): col = lane&15, row = (lane>>4)*4 + reg
  const int orow0 = br * BM + am + (lane >> 4) * 4;
  const int ocol0 = bc * BN + an + fr;
#pragma unroll
  for (int i = 0; i < 2; ++i) {
#pragma unroll
    for (int j = 0; j < 4; ++j) {
      const int col = ocol0 + j * 16;
      const float bv = bias[col];
      const int row = orow0 + i * 16;
#pragma unroll
      for (int r = 0; r < 4; ++r)
        out[(int64_t)(row + r) * N + col] = acc[i][j][r] + bv;
    }
  }
}

// ---------- correctness fallback if workspace too small ----------
__global__ __launch_bounds__(256) void fallback_kernel(
    const float* __restrict__ x, const float* __restrict__ wm,
    const float* __restrict__ wsp, const float* __restrict__ bm,
    const float* __restrict__ bsp, const float* __restrict__ nw,
    const float* __restrict__ nb, float* __restrict__ out)
{
  int64_t idx = (int64_t)blockIdx.x * 256 + threadIdx.x;
  if (idx >= (int64_t)M * N) return;
  int b = (int)(idx >> 12);
  int o = (int)(idx & (N - 1));
  const float* xr = x + (int64_t)b * K;
  const float* wmr = wm + (int64_t)o * K;
  const float* wsr = wsp + (int64_t)o * K;
  const float* nwr = nw + (int64_t)o * K;
  float s = 0.f;
  for (int k = 0; k < K; ++k)
    s += xr[k] * (wmr[k] + nwr[k] * fmaxf(__expf(wsr[k]), EPS));
  out[idx] = s + bm[o] + nb[o] * fmaxf(__expf(bsp[o]), EPS);
}

extern "C" void kernel_launch(void* const* d_in, const int* in_sizes, int n_in,
                              void* d_out, int out_size, void* d_ws, size_t ws_size,
                              hipStream_t stream) {
  const float* x   = (const float*)d_in[0];
  const float* wm  = (const float*)d_in[1];
  const float* wsp = (const float*)d_in[2];
  const float* bm  = (const float*)d_in[3];
  const float* bsp = (const float*)d_in[4];
  const float* nw  = (const float*)d_in[5];
  const float* nb  = (const float*)d_in[6];
  float* out = (float*)d_out;

  const size_t w_bytes = (size_t)N * K * 2;   // 33.5 MB bf16 weight
  const size_t x_bytes = (size_t)M * K * 2;   // 8.4 MB bf16 x
  const size_t b_bytes = (size_t)N * 4;       // bias fp32
  if (ws_size < w_bytes + x_bytes + b_bytes) {
    fallback_kernel<<<(int)(((int64_t)M * N + 255) / 256), 256, 0, stream>>>(
        x, wm, wsp, bm, bsp, nw, nb, out);
    return;
  }

  char* ws = (char*)d_ws;
  unsigned short* w_bf = (unsigned short*)ws;
  unsigned short* x_bf = (unsigned short*)(ws + w_bytes);
  float* bias = (float*)(ws + w_bytes + x_bytes);

  prep_kernel<<<2048, 256, 0, stream>>>(wm, wsp, nw, bm, bsp, nb, x, w_bf, x_bf, bias);
  gemm_kernel<<<(M / BM) * (N / BN), 256, 0, stream>>>(x_bf, w_bf, bias, out);
}